// Round 1
// baseline (156.417 us; speedup 1.0000x reference)
//
#include <hip/hip_runtime.h>
#include <hip/hip_bf16.h>

typedef __bf16 bf16x8 __attribute__((ext_vector_type(8)));
typedef float  f32x4  __attribute__((ext_vector_type(4)));
typedef short  short8 __attribute__((ext_vector_type(8)));
typedef short  short4v __attribute__((ext_vector_type(4)));

#define BM 128
#define BN 128
#define BK 64
#define KDE_IGNORE (-100)

__device__ __forceinline__ f32x4 mfma16x16(bf16x8 a, bf16x8 b, f32x4 c) {
  return __builtin_amdgcn_mfma_f32_16x16x32_bf16(a, b, c, 0, 0, 0);
}

// Kernel 1: per-row squared norms (fp32, exact) + optional bf16 copy.
// One wave per row; assumes D multiple of 256 handled by loop (D=256 here).
template<bool CONV>
__global__ void norms_conv_kernel(const float* __restrict__ x, float* __restrict__ nrm,
                                  short* __restrict__ xb, int rows, int D) {
  int row = blockIdx.x * 4 + (threadIdx.x >> 6);
  int lane = threadIdx.x & 63;
  if (row >= rows) return;
  float s = 0.0f;
  for (int d0 = lane * 4; d0 < D; d0 += 256) {
    float4 v = *reinterpret_cast<const float4*>(x + (size_t)row * D + d0);
    if (CONV) {
      union { short4v sv; __bf16 h[4]; } u;
      u.h[0] = (__bf16)v.x; u.h[1] = (__bf16)v.y;
      u.h[2] = (__bf16)v.z; u.h[3] = (__bf16)v.w;
      *reinterpret_cast<short4v*>(xb + (size_t)row * D + d0) = u.sv;
    }
    s += v.x * v.x + v.y * v.y + v.z * v.z + v.w * v.w;
  }
#pragma unroll
  for (int off = 32; off >= 1; off >>= 1) s += __shfl_xor(s, off);
  if (lane == 0) nrm[row] = s;
}

// Kernel 2: fused tiled GEMM (pred . supp^T) -> exp -> masked row reduction.
// 128x128 tile, BK=64, 4 waves in 2x2 (64x64 each, 4x4 tiles of 16x16).
template<bool PRE>
__global__ __launch_bounds__(256, 2)
void kde_gemm_kernel(const float* __restrict__ predF, const float* __restrict__ suppF,
                     const short* __restrict__ predB, const short* __restrict__ suppB,
                     const int* __restrict__ tgt, const int* __restrict__ suppT,
                     const float* __restrict__ pn, const float* __restrict__ sn,
                     float* __restrict__ denomG, float* __restrict__ numerG,
                     int D, int nbN) {
  __shared__ __align__(16) short As[BM * BK];
  __shared__ __align__(16) short Bs[BN * BK];

  const int bid = blockIdx.x;
  const int mb = bid / nbN;
  const int nb = bid % nbN;
  const int m0 = mb * BM, n0 = nb * BN;
  const int t = threadIdx.x;
  const int lane = t & 63;
  const int wid = t >> 6;
  const int wm = (wid >> 1) * 64;   // wave row offset within tile
  const int wn = (wid & 1) * 64;    // wave col offset within tile
  const int lr = lane >> 4;         // 0..3
  const int lc = lane & 15;         // 0..15

  f32x4 acc[4][4] = {};

  for (int kt = 0; kt < D; kt += BK) {
    // ---- stage A (pred rows) and B (supp rows) into LDS, bf16, XOR-swizzled
#pragma unroll
    for (int it = 0; it < 4; ++it) {
      int c = it * 256 + t;           // 16B-chunk index 0..1023
      int row = c >> 3;               // 0..127
      int col8 = c & 7;               // 8-elem chunk within row (BK=64 -> 8 chunks)
      int swz = ((col8 ^ (row & 7)) << 3);  // swizzled element offset
      short8 pv, sv;
      if (PRE) {
        pv = *reinterpret_cast<const short8*>(predB + (size_t)(m0 + row) * D + kt + col8 * 8);
        sv = *reinterpret_cast<const short8*>(suppB + (size_t)(n0 + row) * D + kt + col8 * 8);
      } else {
        const float4* ga = reinterpret_cast<const float4*>(predF + (size_t)(m0 + row) * D + kt + col8 * 8);
        const float4* gb = reinterpret_cast<const float4*>(suppF + (size_t)(n0 + row) * D + kt + col8 * 8);
        float4 a0 = ga[0], a1 = ga[1];
        float4 b0 = gb[0], b1 = gb[1];
        union { short8 v; __bf16 h[8]; } ua, ub;
        ua.h[0] = (__bf16)a0.x; ua.h[1] = (__bf16)a0.y; ua.h[2] = (__bf16)a0.z; ua.h[3] = (__bf16)a0.w;
        ua.h[4] = (__bf16)a1.x; ua.h[5] = (__bf16)a1.y; ua.h[6] = (__bf16)a1.z; ua.h[7] = (__bf16)a1.w;
        ub.h[0] = (__bf16)b0.x; ub.h[1] = (__bf16)b0.y; ub.h[2] = (__bf16)b0.z; ub.h[3] = (__bf16)b0.w;
        ub.h[4] = (__bf16)b1.x; ub.h[5] = (__bf16)b1.y; ub.h[6] = (__bf16)b1.z; ub.h[7] = (__bf16)b1.w;
        pv = ua.v; sv = ub.v;
      }
      *reinterpret_cast<short8*>(&As[row * BK + swz]) = pv;
      *reinterpret_cast<short8*>(&Bs[row * BK + swz]) = sv;
    }
    __syncthreads();

    // ---- compute: 2 k-steps of 32
#pragma unroll
    for (int ks = 0; ks < BK; ks += 32) {
      bf16x8 af[4], bf[4];
#pragma unroll
      for (int mt = 0; mt < 4; ++mt) {
        int r = wm + mt * 16 + lc;
        int chunk = ((ks >> 3) + lr) ^ (r & 7);
        af[mt] = *reinterpret_cast<const bf16x8*>(&As[r * BK + chunk * 8]);
      }
#pragma unroll
      for (int nt = 0; nt < 4; ++nt) {
        int r = wn + nt * 16 + lc;
        int chunk = ((ks >> 3) + lr) ^ (r & 7);
        bf[nt] = *reinterpret_cast<const bf16x8*>(&Bs[r * BK + chunk * 8]);
      }
#pragma unroll
      for (int mt = 0; mt < 4; ++mt)
#pragma unroll
        for (int nt = 0; nt < 4; ++nt)
          acc[mt][nt] = mfma16x16(af[mt], bf[nt], acc[mt][nt]);
    }
    __syncthreads();
  }

  // ---- fused epilogue: e = exp(-max(pn+sn-2c,0)/256), accumulate denom/numer per m
  const float SC = 1.4426950408889634f / 128.0f;  // 2*log2(e)/256
  float pnh[4][4]; int tmv[4][4];
#pragma unroll
  for (int mt = 0; mt < 4; ++mt)
#pragma unroll
    for (int rg = 0; rg < 4; ++rg) {
      int m = m0 + wm + mt * 16 + lr * 4 + rg;   // C/D layout: row=(lane>>4)*4+reg
      pnh[mt][rg] = pn[m] * (0.5f * SC);
      tmv[mt][rg] = tgt[m];
    }
  float dac[4][4] = {}, nac[4][4] = {};
#pragma unroll
  for (int nt = 0; nt < 4; ++nt) {
    int j = n0 + wn + nt * 16 + lc;              // C/D layout: col=lane&15
    float snh = sn[j] * (0.5f * SC);
    int stv = suppT[j];
#pragma unroll
    for (int mt = 0; mt < 4; ++mt)
#pragma unroll
      for (int rg = 0; rg < 4; ++rg) {
        float x = fmaf(acc[mt][nt][rg], SC, -(pnh[mt][rg] + snh));
        x = fminf(x, 0.0f);                      // sq = max(sq, 0)
        float e = exp2f(x);
        dac[mt][rg] += e;
        nac[mt][rg] += (stv == tmv[mt][rg]) ? e : 0.0f;
      }
  }
  // reduce over the 16 lanes sharing the same m (lc dimension)
#pragma unroll
  for (int off = 1; off < 16; off <<= 1) {
#pragma unroll
    for (int mt = 0; mt < 4; ++mt)
#pragma unroll
      for (int rg = 0; rg < 4; ++rg) {
        dac[mt][rg] += __shfl_xor(dac[mt][rg], off);
        nac[mt][rg] += __shfl_xor(nac[mt][rg], off);
      }
  }
  if (lc == 0) {
#pragma unroll
    for (int mt = 0; mt < 4; ++mt)
#pragma unroll
      for (int rg = 0; rg < 4; ++rg) {
        int m = m0 + wm + mt * 16 + lr * 4 + rg;
        atomicAdd(&denomG[m], dac[mt][rg]);
        atomicAdd(&numerG[m], nac[mt][rg]);
      }
  }
}

// Kernel 3: loss = mean over valid m of -log(clip(numer/clip(denom,eps),eps))
__global__ void finalize_kernel(const float* __restrict__ denomG, const float* __restrict__ numerG,
                                const int* __restrict__ tgt, float* __restrict__ out, int M) {
  __shared__ float sS[4];
  __shared__ int sC[4];
  float s = 0.0f; int cnt = 0;
  for (int m = threadIdx.x; m < M; m += 256) {
    int tg = tgt[m];
    if (tg != KDE_IGNORE) {
      float den = fmaxf(denomG[m], 1e-10f);
      float p = fmaxf(numerG[m] / den, 1e-10f);
      s -= logf(p);
      cnt++;
    }
  }
#pragma unroll
  for (int off = 32; off >= 1; off >>= 1) {
    s += __shfl_xor(s, off);
    cnt += __shfl_xor(cnt, off);
  }
  int wid = threadIdx.x >> 6, lane = threadIdx.x & 63;
  if (lane == 0) { sS[wid] = s; sC[wid] = cnt; }
  __syncthreads();
  if (threadIdx.x == 0) {
    float ts = sS[0] + sS[1] + sS[2] + sS[3];
    int tc = sC[0] + sC[1] + sC[2] + sC[3];
    out[0] = ts / (float)(tc > 1 ? tc : 1);
  }
}

extern "C" void kernel_launch(void* const* d_in, const int* in_sizes, int n_in,
                              void* d_out, int out_size, void* d_ws, size_t ws_size,
                              hipStream_t stream) {
  const float* supp  = (const float*)d_in[0];   // (N, D)
  const float* pred  = (const float*)d_in[1];   // (M, D)
  const int*   suppT = (const int*)d_in[2];     // (N,)
  const int*   tgt   = (const int*)d_in[3];     // (M,)
  const int N = in_sizes[2];
  const int M = in_sizes[3];
  const int D = in_sizes[0] / N;                // 256

  float* pn     = (float*)d_ws;                 // M
  float* sn     = pn + M;                       // N
  float* denomG = sn + N;                       // M
  float* numerG = denomG + M;                   // M
  short* predB  = (short*)(numerG + M);         // M*D bf16
  short* suppB  = predB + (size_t)M * D;        // N*D bf16

  size_t need_small = sizeof(float) * (size_t)(3 * M + N);
  size_t need_big   = need_small + sizeof(short) * ((size_t)(M + N) * D);
  bool pre = (ws_size >= need_big);

  hipMemsetAsync(denomG, 0, sizeof(float) * 2 * (size_t)M, stream);

  if (pre) {
    norms_conv_kernel<true><<<dim3((M + 3) / 4), dim3(256), 0, stream>>>(pred, pn, predB, M, D);
    norms_conv_kernel<true><<<dim3((N + 3) / 4), dim3(256), 0, stream>>>(supp, sn, suppB, N, D);
  } else {
    norms_conv_kernel<false><<<dim3((M + 3) / 4), dim3(256), 0, stream>>>(pred, pn, nullptr, M, D);
    norms_conv_kernel<false><<<dim3((N + 3) / 4), dim3(256), 0, stream>>>(supp, sn, nullptr, N, D);
  }

  int nbN = N / BN, nbM = M / BM;
  dim3 grid(nbM * nbN);
  if (pre) {
    kde_gemm_kernel<true><<<grid, dim3(256), 0, stream>>>(
        pred, supp, predB, suppB, tgt, suppT, pn, sn, denomG, numerG, D, nbN);
  } else {
    kde_gemm_kernel<false><<<grid, dim3(256), 0, stream>>>(
        pred, supp, predB, suppB, tgt, suppT, pn, sn, denomG, numerG, D, nbN);
  }

  finalize_kernel<<<dim3(1), dim3(256), 0, stream>>>(denomG, numerG, tgt, (float*)d_out, M);
}

// Round 2
// 86.314 us; speedup vs baseline: 1.8122x; 1.8122x over previous
//
#include <hip/hip_runtime.h>
#include <hip/hip_bf16.h>

typedef __bf16 bf16x8 __attribute__((ext_vector_type(8)));
typedef float  f32x4  __attribute__((ext_vector_type(4)));
typedef short  short8 __attribute__((ext_vector_type(8)));

#define KDE_IGNORE (-100)
#define GS   8        // N slices (== #XCDs)
#define GBM  128      // m rows per block
#define GBN  64       // n cols per iteration
#define GD   256      // K (full depth, in registers for A)

__device__ __forceinline__ f32x4 mfma16x16(bf16x8 a, bf16x8 b, f32x4 c) {
  return __builtin_amdgcn_mfma_f32_16x16x32_bf16(a, b, c, 0, 0, 0);
}

// ---- Kernel 1: supp row norms (fp32 exact) + optional linear bf16 copy.
// 2 rows per wave (32 lanes each), 8 rows per 256-thread block.
template<bool CONV>
__global__ void supp_prep_kernel(const float* __restrict__ supp, float* __restrict__ sn,
                                 short* __restrict__ suppB, int N) {
  int row = blockIdx.x * 8 + ((threadIdx.x >> 6) << 1) + ((threadIdx.x & 63) >> 5);
  int c = threadIdx.x & 31;                 // 16B bf16 chunk (8 elems)
  const float* src = supp + (size_t)row * GD + c * 8;
  float4 a = *reinterpret_cast<const float4*>(src);
  float4 b = *reinterpret_cast<const float4*>(src + 4);
  if (CONV) {
    union { short8 v; __bf16 h[8]; } u;
    u.h[0] = (__bf16)a.x; u.h[1] = (__bf16)a.y; u.h[2] = (__bf16)a.z; u.h[3] = (__bf16)a.w;
    u.h[4] = (__bf16)b.x; u.h[5] = (__bf16)b.y; u.h[6] = (__bf16)b.z; u.h[7] = (__bf16)b.w;
    *reinterpret_cast<short8*>(suppB + (size_t)row * GD + c * 8) = u.v;
  }
  float s = a.x*a.x + a.y*a.y + a.z*a.z + a.w*a.w
          + b.x*b.x + b.y*b.y + b.z*b.z + b.w*b.w;
#pragma unroll
  for (int off = 16; off >= 1; off >>= 1) s += __shfl_xor(s, off, 32);
  if (c == 0) sn[row] = s;
}

// ---- B-chunk loader (16B of bf16 = 8 elems)
template<bool PRE>
__device__ __forceinline__ short8 load_chunk(const float* suppF, const short* suppB,
                                             int row, int j) {
  if (PRE) {
    return *reinterpret_cast<const short8*>(suppB + (size_t)row * GD + j * 8);
  } else {
    const float* p = suppF + (size_t)row * GD + j * 8;
    float4 a = *reinterpret_cast<const float4*>(p);
    float4 b = *reinterpret_cast<const float4*>(p + 4);
    union { short8 v; __bf16 h[8]; } u;
    u.h[0] = (__bf16)a.x; u.h[1] = (__bf16)a.y; u.h[2] = (__bf16)a.z; u.h[3] = (__bf16)a.w;
    u.h[4] = (__bf16)b.x; u.h[5] = (__bf16)b.y; u.h[6] = (__bf16)b.z; u.h[7] = (__bf16)b.w;
    return u.v;
  }
}

// ---- Kernel 2: fused GEMM + exp + masked row-accumulate, atomic-free.
// Block: 256 thr = 4 waves (2m x 2n). Wave tile per iter: 64m x 32n, full K=256.
// A (pred) held in registers for the whole block lifetime; B double-buffered in LDS.
template<bool PRE>
__global__ __launch_bounds__(256, 1)
void kde_gemm_kernel(const float* __restrict__ pred, const float* __restrict__ suppF,
                     const short* __restrict__ suppB,
                     const int* __restrict__ tgt, const int* __restrict__ suppT,
                     const float* __restrict__ sn,
                     float* __restrict__ denomP, float* __restrict__ numerP,
                     int M, int N) {
  __shared__ __align__(16) short Bs[2][GBN * GD];   // 2 x 32 KiB

  const int bid = blockIdx.x;
  const int mb  = bid >> 3;           // 0..M/128-1
  const int s   = bid & 7;            // slice == XCD (bid%8 round-robin)
  const int m0  = mb * GBM;
  const int nslice = N >> 3;          // 2048
  const int nbase  = s * nslice;
  const int niter  = nslice / GBN;    // 32
  const int t    = threadIdx.x;
  const int lane = t & 63;
  const int wid  = t >> 6;
  const int wm   = (wid >> 1) * 64;
  const int wnl  = (wid & 1) * 32;
  const int lr = lane >> 4, lc = lane & 15;

  // ---- A fragments: full K in registers (bf16), converted from fp32 once.
  bf16x8 af[4][8];
#pragma unroll
  for (int mt = 0; mt < 4; ++mt) {
    const float* base = pred + (size_t)(m0 + wm + mt * 16 + lc) * GD + lr * 8;
#pragma unroll
    for (int kk = 0; kk < 8; ++kk) {
      float4 a = *reinterpret_cast<const float4*>(base + kk * 32);
      float4 b = *reinterpret_cast<const float4*>(base + kk * 32 + 4);
      union { bf16x8 v; __bf16 h[8]; } u;
      u.h[0] = (__bf16)a.x; u.h[1] = (__bf16)a.y; u.h[2] = (__bf16)a.z; u.h[3] = (__bf16)a.w;
      u.h[4] = (__bf16)b.x; u.h[5] = (__bf16)b.y; u.h[6] = (__bf16)b.z; u.h[7] = (__bf16)b.w;
      af[mt][kk] = u.v;
    }
  }
  int tmv[4][4];
#pragma unroll
  for (int mt = 0; mt < 4; ++mt)
#pragma unroll
    for (int rg = 0; rg < 4; ++rg)
      tmv[mt][rg] = tgt[m0 + wm + mt * 16 + lr * 4 + rg];

  float dac[4][4] = {}, nac[4][4] = {};

  // ---- stage iter 0 (swizzled: 16B chunk j -> j ^ (row&31))
#pragma unroll
  for (int i = 0; i < 8; ++i) {
    int C = i * 256 + t; int row = C >> 5; int j = C & 31;
    short8 v = load_chunk<PRE>(suppF, suppB, nbase + row, j);
    *reinterpret_cast<short8*>(&Bs[0][row * GD + ((j ^ (row & 31)) << 3)]) = v;
  }
  __syncthreads();

  const float SC  = 1.4426950408889634f / 128.0f;   // log2e/128  (for 2*dot)
  const float SCH = 1.4426950408889634f / 256.0f;   // log2e/256  (for sn)

  for (int it = 0; it < niter; ++it) {
    const int cur = it & 1;
    const int n0 = nbase + it * GBN;
    const bool more = (it + 1 < niter);

    // T14: issue next tile's global loads early
    short8 sreg[8];
    if (more) {
      const int n1 = n0 + GBN;
#pragma unroll
      for (int i = 0; i < 8; ++i) {
        int C = i * 256 + t; int row = C >> 5; int j = C & 31;
        sreg[i] = load_chunk<PRE>(suppF, suppB, n1 + row, j);
      }
    }
    // per-iter epilogue metadata
    float snv[2]; int stv[2];
#pragma unroll
    for (int nt = 0; nt < 2; ++nt) {
      int j = n0 + wnl + nt * 16 + lc;
      snv[nt] = sn[j]; stv[nt] = suppT[j];
    }

    // MFMA over full K
    f32x4 acc[4][2] = {};
#pragma unroll
    for (int ks = 0; ks < 8; ++ks) {
      bf16x8 bf[2];
#pragma unroll
      for (int nt = 0; nt < 2; ++nt) {
        int r = wnl + nt * 16 + lc;
        int cs = (ks * 4 + lr) ^ (r & 31);
        bf[nt] = *reinterpret_cast<const bf16x8*>(&Bs[cur][r * GD + (cs << 3)]);
      }
#pragma unroll
      for (int mt = 0; mt < 4; ++mt)
#pragma unroll
        for (int nt = 0; nt < 2; ++nt)
          acc[mt][nt] = mfma16x16(af[mt][ks], bf[nt], acc[mt][nt]);
    }

    // write-late: staged regs -> other buffer (read last at it-1, safe)
    if (more) {
#pragma unroll
      for (int i = 0; i < 8; ++i) {
        int C = i * 256 + t; int row = C >> 5; int j = C & 31;
        *reinterpret_cast<short8*>(&Bs[cur ^ 1][row * GD + ((j ^ (row & 31)) << 3)]) = sreg[i];
      }
    }

    // fused epilogue: e = 2^((2c - sn)*log2e/256); pn factor cancels in numer/denom
#pragma unroll
    for (int nt = 0; nt < 2; ++nt) {
      float sh = -snv[nt] * SCH;
#pragma unroll
      for (int mt = 0; mt < 4; ++mt)
#pragma unroll
        for (int rg = 0; rg < 4; ++rg) {
          float e = exp2f(fmaf(acc[mt][nt][rg], SC, sh));
          dac[mt][rg] += e;
          nac[mt][rg] += (stv[nt] == tmv[mt][rg]) ? e : 0.0f;
        }
    }
    __syncthreads();
  }

  // reduce over the 16 lanes (lc) sharing each m, write slot partials
#pragma unroll
  for (int off = 1; off < 16; off <<= 1) {
#pragma unroll
    for (int mt = 0; mt < 4; ++mt)
#pragma unroll
      for (int rg = 0; rg < 4; ++rg) {
        dac[mt][rg] += __shfl_xor(dac[mt][rg], off);
        nac[mt][rg] += __shfl_xor(nac[mt][rg], off);
      }
  }
  if (lc == 0) {
    const int slot = s * 2 + (wid & 1);     // 16 slots per m
#pragma unroll
    for (int mt = 0; mt < 4; ++mt)
#pragma unroll
      for (int rg = 0; rg < 4; ++rg) {
        int m = m0 + wm + mt * 16 + lr * 4 + rg;
        denomP[(size_t)slot * M + m] = dac[mt][rg];
        numerP[(size_t)slot * M + m] = nac[mt][rg];
      }
  }
}

// ---- Kernel 3: per-m sum over 16 slots -> nll, per-block partial sums
__global__ void kde_reduce_kernel(const float* __restrict__ denomP, const float* __restrict__ numerP,
                                  const int* __restrict__ tgt,
                                  float* __restrict__ bsum, float* __restrict__ bcnt, int M) {
  __shared__ float sS[4], sC[4];
  int m = blockIdx.x * 256 + threadIdx.x;
  float den = 0.0f, num = 0.0f;
#pragma unroll
  for (int sl = 0; sl < 16; ++sl) {
    den += denomP[(size_t)sl * M + m];
    num += numerP[(size_t)sl * M + m];
  }
  int tg = tgt[m];
  bool valid = (tg != KDE_IGNORE);
  float p = fmaxf(num / fmaxf(den, 1e-10f), 1e-10f);
  float nll = valid ? -logf(p) : 0.0f;
  float cnt = valid ? 1.0f : 0.0f;
#pragma unroll
  for (int off = 32; off >= 1; off >>= 1) {
    nll += __shfl_xor(nll, off);
    cnt += __shfl_xor(cnt, off);
  }
  int wid = threadIdx.x >> 6, lane = threadIdx.x & 63;
  if (lane == 0) { sS[wid] = nll; sC[wid] = cnt; }
  __syncthreads();
  if (threadIdx.x == 0) {
    bsum[blockIdx.x] = sS[0] + sS[1] + sS[2] + sS[3];
    bcnt[blockIdx.x] = sC[0] + sC[1] + sC[2] + sC[3];
  }
}

__global__ void kde_final_kernel(const float* __restrict__ bsum, const float* __restrict__ bcnt,
                                 float* __restrict__ out, int nb) {
  int tid = threadIdx.x;
  float s = (tid < nb) ? bsum[tid] : 0.0f;
  float c = (tid < nb) ? bcnt[tid] : 0.0f;
#pragma unroll
  for (int off = 32; off >= 1; off >>= 1) {
    s += __shfl_xor(s, off);
    c += __shfl_xor(c, off);
  }
  if (tid == 0) out[0] = s / fmaxf(c, 1.0f);
}

extern "C" void kernel_launch(void* const* d_in, const int* in_sizes, int n_in,
                              void* d_out, int out_size, void* d_ws, size_t ws_size,
                              hipStream_t stream) {
  const float* supp  = (const float*)d_in[0];   // (N, 256)
  const float* pred  = (const float*)d_in[1];   // (M, 256)
  const int*   suppT = (const int*)d_in[2];     // (N,)
  const int*   tgt   = (const int*)d_in[3];     // (M,)
  const int N = in_sizes[2];
  const int M = in_sizes[3];

  float* sn     = (float*)d_ws;                   // N
  float* denomP = sn + N;                         // 16*M
  float* numerP = denomP + 16 * (size_t)M;        // 16*M
  float* bsum   = numerP + 16 * (size_t)M;        // 16
  float* bcnt   = bsum + 16;                      // 16
  short* suppB  = (short*)(bcnt + 16);            // N*256 bf16

  size_t small = sizeof(float) * ((size_t)N + 32 * (size_t)M + 32);
  bool pre = ws_size >= small + sizeof(short) * (size_t)N * GD;

  if (pre) supp_prep_kernel<true ><<<dim3(N / 8), dim3(256), 0, stream>>>(supp, sn, suppB, N);
  else     supp_prep_kernel<false><<<dim3(N / 8), dim3(256), 0, stream>>>(supp, sn, nullptr, N);

  dim3 grid((M / GBM) * GS);   // bid = mb*8 + s  -> s == bid%8 (XCD-aligned slices)
  if (pre) kde_gemm_kernel<true ><<<grid, dim3(256), 0, stream>>>(
      pred, supp, suppB, tgt, suppT, sn, denomP, numerP, M, N);
  else     kde_gemm_kernel<false><<<grid, dim3(256), 0, stream>>>(
      pred, supp, suppB, tgt, suppT, sn, denomP, numerP, M, N);

  kde_reduce_kernel<<<dim3(M / 256), dim3(256), 0, stream>>>(denomP, numerP, tgt, bsum, bcnt, M);
  kde_final_kernel<<<dim3(1), dim3(64), 0, stream>>>(bsum, bcnt, (float*)d_out, M / 256);
}

// Round 3
// 76.401 us; speedup vs baseline: 2.0473x; 1.1298x over previous
//
#include <hip/hip_runtime.h>
#include <hip/hip_bf16.h>

typedef __bf16 bf16x8 __attribute__((ext_vector_type(8)));
typedef float  f32x4  __attribute__((ext_vector_type(4)));
typedef short  short8 __attribute__((ext_vector_type(8)));

#define KDE_IGNORE (-100)
#define GS   8        // N slices (== #XCDs)
#define GBM  64       // m rows per block
#define GBN  64       // n cols per iteration
#define GD   256      // K (full depth, in registers for A)

__device__ __forceinline__ f32x4 mfma16x16(bf16x8 a, bf16x8 b, f32x4 c) {
  return __builtin_amdgcn_mfma_f32_16x16x32_bf16(a, b, c, 0, 0, 0);
}

// ---- Kernel 1: supp row norms (fp32 exact) + optional linear bf16 copy.
template<bool CONV>
__global__ void supp_prep_kernel(const float* __restrict__ supp, float* __restrict__ sn,
                                 short* __restrict__ suppB, int N) {
  int row = blockIdx.x * 8 + ((threadIdx.x >> 6) << 1) + ((threadIdx.x & 63) >> 5);
  int c = threadIdx.x & 31;                 // 16B bf16 chunk (8 elems)
  const float* src = supp + (size_t)row * GD + c * 8;
  float4 a = *reinterpret_cast<const float4*>(src);
  float4 b = *reinterpret_cast<const float4*>(src + 4);
  if (CONV) {
    union { short8 v; __bf16 h[8]; } u;
    u.h[0] = (__bf16)a.x; u.h[1] = (__bf16)a.y; u.h[2] = (__bf16)a.z; u.h[3] = (__bf16)a.w;
    u.h[4] = (__bf16)b.x; u.h[5] = (__bf16)b.y; u.h[6] = (__bf16)b.z; u.h[7] = (__bf16)b.w;
    *reinterpret_cast<short8*>(suppB + (size_t)row * GD + c * 8) = u.v;
  }
  float s = a.x*a.x + a.y*a.y + a.z*a.z + a.w*a.w
          + b.x*b.x + b.y*b.y + b.z*b.z + b.w*b.w;
#pragma unroll
  for (int off = 16; off >= 1; off >>= 1) s += __shfl_xor(s, off, 32);
  if (c == 0) sn[row] = s;
}

// ---- B-chunk loader (16B of bf16 = 8 elems)
template<bool PRE>
__device__ __forceinline__ short8 load_chunk(const float* suppF, const short* suppB,
                                             int row, int j) {
  if (PRE) {
    return *reinterpret_cast<const short8*>(suppB + (size_t)row * GD + j * 8);
  } else {
    const float* p = suppF + (size_t)row * GD + j * 8;
    float4 a = *reinterpret_cast<const float4*>(p);
    float4 b = *reinterpret_cast<const float4*>(p + 4);
    union { short8 v; __bf16 h[8]; } u;
    u.h[0] = (__bf16)a.x; u.h[1] = (__bf16)a.y; u.h[2] = (__bf16)a.z; u.h[3] = (__bf16)a.w;
    u.h[4] = (__bf16)b.x; u.h[5] = (__bf16)b.y; u.h[6] = (__bf16)b.z; u.h[7] = (__bf16)b.w;
    return u.v;
  }
}

// ---- Kernel 2: fused GEMM + exp + masked row-accumulate, atomic-free.
// Block: 256 thr = 4 waves (2m x 2n) over a 64m tile; per iter 64n, full K=256.
// A (pred) in registers for the block lifetime; B double-buffered in LDS.
// Grid = (M/64)*8 = 512 blocks -> 2 blocks/CU (LDS 2x64KB=128KB), 8 waves/CU.
template<bool PRE>
__global__ __launch_bounds__(256, 2)
void kde_gemm_kernel(const float* __restrict__ pred, const float* __restrict__ suppF,
                     const short* __restrict__ suppB,
                     const int* __restrict__ tgt, const int* __restrict__ suppT,
                     const float* __restrict__ sn,
                     float* __restrict__ denomP, float* __restrict__ numerP,
                     int M, int N) {
  __shared__ __align__(16) short Bs[2][GBN * GD];   // 2 x 32 KiB

  const int bid = blockIdx.x;
  const int mb  = bid >> 3;           // 0..M/64-1
  const int s   = bid & 7;            // slice == XCD (bid%8 round-robin)
  const int m0  = mb * GBM;
  const int nslice = N >> 3;          // 2048
  const int nbase  = s * nslice;
  const int niter  = nslice / GBN;    // 32
  const int t    = threadIdx.x;
  const int lane = t & 63;
  const int wid  = t >> 6;
  const int wm   = (wid >> 1) * 32;
  const int wnl  = (wid & 1) * 32;
  const int lr = lane >> 4, lc = lane & 15;

  // ---- A fragments: full K in registers (bf16), converted from fp32 once.
  bf16x8 af[2][8];
#pragma unroll
  for (int mt = 0; mt < 2; ++mt) {
    const float* base = pred + (size_t)(m0 + wm + mt * 16 + lc) * GD + lr * 8;
#pragma unroll
    for (int kk = 0; kk < 8; ++kk) {
      float4 a = *reinterpret_cast<const float4*>(base + kk * 32);
      float4 b = *reinterpret_cast<const float4*>(base + kk * 32 + 4);
      union { bf16x8 v; __bf16 h[8]; } u;
      u.h[0] = (__bf16)a.x; u.h[1] = (__bf16)a.y; u.h[2] = (__bf16)a.z; u.h[3] = (__bf16)a.w;
      u.h[4] = (__bf16)b.x; u.h[5] = (__bf16)b.y; u.h[6] = (__bf16)b.z; u.h[7] = (__bf16)b.w;
      af[mt][kk] = u.v;
    }
  }
  int tmv[2][4];
#pragma unroll
  for (int mt = 0; mt < 2; ++mt)
#pragma unroll
    for (int rg = 0; rg < 4; ++rg)
      tmv[mt][rg] = tgt[m0 + wm + mt * 16 + lr * 4 + rg];

  float dac[2][4] = {}, nac[2][4] = {};

  // ---- stage iter 0 (swizzled: 16B chunk j -> j ^ (row&31))
#pragma unroll
  for (int i = 0; i < 8; ++i) {
    int C = i * 256 + t; int row = C >> 5; int j = C & 31;
    short8 v = load_chunk<PRE>(suppF, suppB, nbase + row, j);
    *reinterpret_cast<short8*>(&Bs[0][row * GD + ((j ^ (row & 31)) << 3)]) = v;
  }
  __syncthreads();

  const float SC  = 1.4426950408889634f / 128.0f;   // log2e/128  (for 2*dot)
  const float SCH = 1.4426950408889634f / 256.0f;   // log2e/256  (for sn)

  for (int it = 0; it < niter; ++it) {
    const int cur = it & 1;
    const int n0 = nbase + it * GBN;
    const bool more = (it + 1 < niter);

    // T14: issue next tile's global loads early
    short8 sreg[8];
    if (more) {
      const int n1 = n0 + GBN;
#pragma unroll
      for (int i = 0; i < 8; ++i) {
        int C = i * 256 + t; int row = C >> 5; int j = C & 31;
        sreg[i] = load_chunk<PRE>(suppF, suppB, n1 + row, j);
      }
    }
    // per-iter epilogue metadata (latency hidden under MFMA)
    float snv[2]; int stv[2];
#pragma unroll
    for (int nt = 0; nt < 2; ++nt) {
      int j = n0 + wnl + nt * 16 + lc;
      snv[nt] = sn[j]; stv[nt] = suppT[j];
    }

    // MFMA over full K
    f32x4 acc[2][2] = {};
    __builtin_amdgcn_s_setprio(1);
#pragma unroll
    for (int ks = 0; ks < 8; ++ks) {
      bf16x8 bf[2];
#pragma unroll
      for (int nt = 0; nt < 2; ++nt) {
        int r = wnl + nt * 16 + lc;
        int cs = (ks * 4 + lr) ^ (r & 31);
        bf[nt] = *reinterpret_cast<const bf16x8*>(&Bs[cur][r * GD + (cs << 3)]);
      }
#pragma unroll
      for (int mt = 0; mt < 2; ++mt)
#pragma unroll
        for (int nt = 0; nt < 2; ++nt)
          acc[mt][nt] = mfma16x16(af[mt][ks], bf[nt], acc[mt][nt]);
    }
    __builtin_amdgcn_s_setprio(0);

    // write-late: staged regs -> other buffer (last read at it-1, safe)
    if (more) {
#pragma unroll
      for (int i = 0; i < 8; ++i) {
        int C = i * 256 + t; int row = C >> 5; int j = C & 31;
        *reinterpret_cast<short8*>(&Bs[cur ^ 1][row * GD + ((j ^ (row & 31)) << 3)]) = sreg[i];
      }
    }

    // fused epilogue: e = 2^((2c - sn)*log2e/256); pn factor cancels in numer/denom
#pragma unroll
    for (int nt = 0; nt < 2; ++nt) {
      float sh = -snv[nt] * SCH;
#pragma unroll
      for (int mt = 0; mt < 2; ++mt)
#pragma unroll
        for (int rg = 0; rg < 4; ++rg) {
          float e = exp2f(fmaf(acc[mt][nt][rg], SC, sh));
          dac[mt][rg] += e;
          nac[mt][rg] += (stv[nt] == tmv[mt][rg]) ? e : 0.0f;
        }
    }
    __syncthreads();
  }

  // reduce over the 16 lanes (lc) sharing each m, write slot partials
#pragma unroll
  for (int off = 1; off < 16; off <<= 1) {
#pragma unroll
    for (int mt = 0; mt < 2; ++mt)
#pragma unroll
      for (int rg = 0; rg < 4; ++rg) {
        dac[mt][rg] += __shfl_xor(dac[mt][rg], off);
        nac[mt][rg] += __shfl_xor(nac[mt][rg], off);
      }
  }
  if (lc == 0) {
    const int slot = s * 2 + (wid & 1);     // 16 slots per m
#pragma unroll
    for (int mt = 0; mt < 2; ++mt)
#pragma unroll
      for (int rg = 0; rg < 4; ++rg) {
        int m = m0 + wm + mt * 16 + lr * 4 + rg;
        denomP[(size_t)slot * M + m] = dac[mt][rg];
        numerP[(size_t)slot * M + m] = nac[mt][rg];
      }
  }
}

// ---- Kernel 3: per-m sum over 16 slots -> nll, per-block partial sums
__global__ void kde_reduce_kernel(const float* __restrict__ denomP, const float* __restrict__ numerP,
                                  const int* __restrict__ tgt,
                                  float* __restrict__ bsum, float* __restrict__ bcnt, int M) {
  __shared__ float sS[4], sC[4];
  int m = blockIdx.x * 256 + threadIdx.x;
  float den = 0.0f, num = 0.0f;
#pragma unroll
  for (int sl = 0; sl < 16; ++sl) {
    den += denomP[(size_t)sl * M + m];
    num += numerP[(size_t)sl * M + m];
  }
  int tg = tgt[m];
  bool valid = (tg != KDE_IGNORE);
  float p = fmaxf(num / fmaxf(den, 1e-10f), 1e-10f);
  float nll = valid ? -logf(p) : 0.0f;
  float cnt = valid ? 1.0f : 0.0f;
#pragma unroll
  for (int off = 32; off >= 1; off >>= 1) {
    nll += __shfl_xor(nll, off);
    cnt += __shfl_xor(cnt, off);
  }
  int wid = threadIdx.x >> 6, lane = threadIdx.x & 63;
  if (lane == 0) { sS[wid] = nll; sC[wid] = cnt; }
  __syncthreads();
  if (threadIdx.x == 0) {
    bsum[blockIdx.x] = sS[0] + sS[1] + sS[2] + sS[3];
    bcnt[blockIdx.x] = sC[0] + sC[1] + sC[2] + sC[3];
  }
}

__global__ void kde_final_kernel(const float* __restrict__ bsum, const float* __restrict__ bcnt,
                                 float* __restrict__ out, int nb) {
  int tid = threadIdx.x;
  float s = (tid < nb) ? bsum[tid] : 0.0f;
  float c = (tid < nb) ? bcnt[tid] : 0.0f;
#pragma unroll
  for (int off = 32; off >= 1; off >>= 1) {
    s += __shfl_xor(s, off);
    c += __shfl_xor(c, off);
  }
  if (tid == 0) out[0] = s / fmaxf(c, 1.0f);
}

extern "C" void kernel_launch(void* const* d_in, const int* in_sizes, int n_in,
                              void* d_out, int out_size, void* d_ws, size_t ws_size,
                              hipStream_t stream) {
  const float* supp  = (const float*)d_in[0];   // (N, 256)
  const float* pred  = (const float*)d_in[1];   // (M, 256)
  const int*   suppT = (const int*)d_in[2];     // (N,)
  const int*   tgt   = (const int*)d_in[3];     // (M,)
  const int N = in_sizes[2];
  const int M = in_sizes[3];

  float* sn     = (float*)d_ws;                   // N
  float* denomP = sn + N;                         // 16*M
  float* numerP = denomP + 16 * (size_t)M;        // 16*M
  float* bsum   = numerP + 16 * (size_t)M;        // 16
  float* bcnt   = bsum + 16;                      // 16
  short* suppB  = (short*)(bcnt + 16);            // N*256 bf16

  size_t small = sizeof(float) * ((size_t)N + 32 * (size_t)M + 32);
  bool pre = ws_size >= small + sizeof(short) * (size_t)N * GD;

  if (pre) supp_prep_kernel<true ><<<dim3(N / 8), dim3(256), 0, stream>>>(supp, sn, suppB, N);
  else     supp_prep_kernel<false><<<dim3(N / 8), dim3(256), 0, stream>>>(supp, sn, nullptr, N);

  dim3 grid((M / GBM) * GS);   // bid = mb*8 + s  -> s == bid%8 (XCD-aligned slices)
  if (pre) kde_gemm_kernel<true ><<<grid, dim3(256), 0, stream>>>(
      pred, supp, suppB, tgt, suppT, sn, denomP, numerP, M, N);
  else     kde_gemm_kernel<false><<<grid, dim3(256), 0, stream>>>(
      pred, supp, suppB, tgt, suppT, sn, denomP, numerP, M, N);

  kde_reduce_kernel<<<dim3(M / 256), dim3(256), 0, stream>>>(denomP, numerP, tgt, bsum, bcnt, M);
  kde_final_kernel<<<dim3(1), dim3(64), 0, stream>>>(bsum, bcnt, (float*)d_out, M / 256);
}